// Round 1
// baseline (634.352 us; speedup 1.0000x reference)
//
#include <hip/hip_runtime.h>

#define IN_F 4096
#define OUT_F 4096
#define BATCH 8192
#define KTOP 3687.0f

typedef float f32x4 __attribute__((ext_vector_type(4)));
typedef short bf16x8 __attribute__((ext_vector_type(8)));          // 8 bf16 = 4 VGPRs
typedef unsigned short ushort8 __attribute__((ext_vector_type(8)));

typedef __attribute__((address_space(1))) void gvoid;
typedef __attribute__((address_space(3))) void lvoid;

__device__ __forceinline__ unsigned short f2bf(float f) {
    unsigned int u = __float_as_uint(f);
    u += 0x7fff + ((u >> 16) & 1);   // round-to-nearest-even
    return (unsigned short)(u >> 16);
}

// ---------------- a_topk = clip(K * softmax(alpha), 0, 1) ----------------
__global__ __launch_bounds__(256) void atopk_kernel(const float* __restrict__ alpha,
                                                    float* __restrict__ atopk) {
    __shared__ float smax[4], ssum[4];
    int tid = threadIdx.x;
    float m = -1e30f;
    for (int i = tid; i < OUT_F; i += 256) m = fmaxf(m, alpha[i]);
    for (int o = 1; o < 64; o <<= 1) m = fmaxf(m, __shfl_xor(m, o));
    if ((tid & 63) == 0) smax[tid >> 6] = m;
    __syncthreads();
    m = fmaxf(fmaxf(smax[0], smax[1]), fmaxf(smax[2], smax[3]));
    float s = 0.f;
    for (int i = tid; i < OUT_F; i += 256) s += expf(alpha[i] - m);
    for (int o = 1; o < 64; o <<= 1) s += __shfl_xor(s, o);
    if ((tid & 63) == 0) ssum[tid >> 6] = s;
    __syncthreads();
    s = ssum[0] + ssum[1] + ssum[2] + ssum[3];
    float inv = 1.0f / s;
    for (int i = tid; i < OUT_F; i += 256) {
        float v = KTOP * expf(alpha[i] - m) * inv;
        atopk[i] = fminf(fmaxf(v, 0.0f), 1.0f);
    }
}

// ---------------- W[r][c] = V[(r-c)&4095][c] * a[(r-c)&4095]  (bf16) ------
__global__ __launch_bounds__(256) void build_w_kernel(const float* __restrict__ V,
                                                      const float* __restrict__ atopk,
                                                      unsigned short* __restrict__ W) {
    int tx = threadIdx.x & 63;
    int ty = threadIdx.x >> 6;
    int c  = blockIdx.x * 64 + tx;
    int r0 = blockIdx.y * 64;
    #pragma unroll
    for (int it = 0; it < 16; ++it) {
        int r = r0 + it * 4 + ty;
        int s = (r - c) & (OUT_F - 1);
        float v = V[s * IN_F + c] * atopk[s];
        W[(long)r * IN_F + c] = f2bf(v);
    }
}

// ---------------- x fp32 -> bf16 ------------------------------------------
__global__ __launch_bounds__(256) void cvt_x_kernel(const float* __restrict__ x,
                                                    unsigned short* __restrict__ xb) {
    long i = ((long)blockIdx.x * 256 + threadIdx.x) * 8;
    const float* p = x + i;
    ushort8 o;
    #pragma unroll
    for (int j = 0; j < 8; ++j) o[j] = f2bf(p[j]);
    *(ushort8*)(xb + i) = o;
}

// ---------------- GEMM: C[M][N] = A[M][K] * Bt[N][K]^T  (bf16 -> f32) -----
// m97 structure: 128x128 tile, BK=64 as two [128][32] half-buffers,
// global_load_lds width 16, 4 waves each computing 64x64 via 4x4 frags of
// 16x16x32 MFMA.
__global__ __launch_bounds__(256) void gemm_kernel(const unsigned short* __restrict__ A,
                                                   const unsigned short* __restrict__ Bt,
                                                   float* __restrict__ C) {
    __shared__ unsigned short As[2][128][32];
    __shared__ unsigned short Bs[2][128][32];

    const int tid = threadIdx.x;
    const int w = tid >> 6;         // wave 0..3
    const int l = tid & 63;         // lane
    const int wr = w >> 1, wc = w & 1;
    const int bn = blockIdx.x, bm = blockIdx.y;

    f32x4 acc[4][4] = {};

    // staging geometry: chunk q (0..15) = 1KB = 16 rows x 32 shorts in half h=q>>3
    const int srow = l >> 2;        // 0..15
    const int scol = (l & 3) * 8;   // 0,8,16,24
    const unsigned short* Abase = A  + ((long)bm * 128) * IN_F;
    const unsigned short* Bbase = Bt + ((long)bn * 128) * IN_F;

    const int lr = l & 15;
    const int lk = (l >> 4) * 8;

    for (int k0 = 0; k0 < IN_F; k0 += 64) {
        #pragma unroll
        for (int i = 0; i < 4; ++i) {
            int q = w * 4 + i;                 // 0..15, wave-uniform
            int h = q >> 3;
            int row = (q & 7) * 16 + srow;
            int kc = k0 + h * 32 + scol;
            __builtin_amdgcn_global_load_lds((gvoid*)(Abase + (long)row * IN_F + kc),
                                             (lvoid*)(&As[0][0][0] + q * 512), 16, 0, 0);
            __builtin_amdgcn_global_load_lds((gvoid*)(Bbase + (long)row * IN_F + kc),
                                             (lvoid*)(&Bs[0][0][0] + q * 512), 16, 0, 0);
        }
        __syncthreads();

        #pragma unroll
        for (int kk = 0; kk < 2; ++kk) {
            bf16x8 af[4], bfr[4];
            #pragma unroll
            for (int m = 0; m < 4; ++m)
                af[m] = *(const bf16x8*)(&As[kk][wr * 64 + m * 16 + lr][lk]);
            #pragma unroll
            for (int n = 0; n < 4; ++n)
                bfr[n] = *(const bf16x8*)(&Bs[kk][wc * 64 + n * 16 + lr][lk]);
            #pragma unroll
            for (int m = 0; m < 4; ++m)
                #pragma unroll
                for (int n = 0; n < 4; ++n)
                    acc[m][n] = __builtin_amdgcn_mfma_f32_16x16x32_bf16(af[m], bfr[n], acc[m][n], 0, 0, 0);
        }
        __syncthreads();
    }

    // epilogue: C/D layout (m89): col = lane&15, row = (lane>>4)*4 + reg
    const long r0 = (long)bm * 128 + wr * 64;
    const int  c0 = bn * 128 + wc * 64;
    const int  rq = (l >> 4) * 4;
    #pragma unroll
    for (int m = 0; m < 4; ++m)
        #pragma unroll
        for (int n = 0; n < 4; ++n)
            #pragma unroll
            for (int v = 0; v < 4; ++v)
                C[(r0 + m * 16 + rq + v) * OUT_F + (c0 + n * 16 + lr)] = acc[m][n][v];
}

extern "C" void kernel_launch(void* const* d_in, const int* in_sizes, int n_in,
                              void* d_out, int out_size, void* d_ws, size_t ws_size,
                              hipStream_t stream) {
    const float* x     = (const float*)d_in[0];
    const float* V     = (const float*)d_in[1];
    const float* alpha = (const float*)d_in[2];
    float* out = (float*)d_out;

    char* ws = (char*)d_ws;
    float* atopk      = (float*)ws;                                        // 16 KB
    unsigned short* W  = (unsigned short*)(ws + 16384);                    // 32 MB
    unsigned short* Xb = (unsigned short*)(ws + 16384 + (size_t)OUT_F * IN_F * 2); // 64 MB

    atopk_kernel<<<1, 256, 0, stream>>>(alpha, atopk);
    build_w_kernel<<<dim3(IN_F / 64, OUT_F / 64), 256, 0, stream>>>(V, atopk, W);
    cvt_x_kernel<<<(BATCH * IN_F / 8) / 256, 256, 0, stream>>>(x, Xb);
    gemm_kernel<<<dim3(OUT_F / 128, BATCH / 128), 256, 0, stream>>>(Xb, W, out);
}

// Round 2
// 547.867 us; speedup vs baseline: 1.1579x; 1.1579x over previous
//
#include <hip/hip_runtime.h>

#define IN_F 4096
#define OUT_F 4096
#define BATCH 8192
#define KTOP 3687.0f
#define NT (IN_F / 64)

typedef float f32x4 __attribute__((ext_vector_type(4)));
typedef short bf16x8 __attribute__((ext_vector_type(8)));
typedef unsigned short ushort8 __attribute__((ext_vector_type(8)));

typedef __attribute__((address_space(1))) void gvoid;
typedef __attribute__((address_space(3))) void lvoid;

__device__ __forceinline__ unsigned short f2bf(float f) {
    unsigned int u = __float_as_uint(f);
    u += 0x7fff + ((u >> 16) & 1);   // round-to-nearest-even
    return (unsigned short)(u >> 16);
}

// ---------------- a_topk = clip(K * softmax(alpha), 0, 1) ----------------
__global__ __launch_bounds__(256) void atopk_kernel(const float* __restrict__ alpha,
                                                    float* __restrict__ atopk) {
    __shared__ float smax[4], ssum[4];
    int tid = threadIdx.x;
    float m = -1e30f;
    for (int i = tid; i < OUT_F; i += 256) m = fmaxf(m, alpha[i]);
    for (int o = 1; o < 64; o <<= 1) m = fmaxf(m, __shfl_xor(m, o));
    if ((tid & 63) == 0) smax[tid >> 6] = m;
    __syncthreads();
    m = fmaxf(fmaxf(smax[0], smax[1]), fmaxf(smax[2], smax[3]));
    float s = 0.f;
    for (int i = tid; i < OUT_F; i += 256) s += expf(alpha[i] - m);
    for (int o = 1; o < 64; o <<= 1) s += __shfl_xor(s, o);
    if ((tid & 63) == 0) ssum[tid >> 6] = s;
    __syncthreads();
    s = ssum[0] + ssum[1] + ssum[2] + ssum[3];
    float inv = 1.0f / s;
    for (int i = tid; i < OUT_F; i += 256) {
        float v = KTOP * expf(alpha[i] - m) * inv;
        atopk[i] = fminf(fmaxf(v, 0.0f), 1.0f);
    }
}

// ---- W[r][c] = V[(r-c)&4095][c] * a[(r-c)&4095]  (bf16), LDS-banded -----
// Block: 64x64 W tile. Coalesced V reads of the 127-row diagonal band into
// LDS; diagonal LDS reads are conflict-free (row stride 64 f32 = 0 mod 32
// banks, col tracks lane).
__global__ __launch_bounds__(256) void build_w_kernel(const float* __restrict__ V,
                                                      const float* __restrict__ atopk,
                                                      unsigned short* __restrict__ W) {
    __shared__ float Vl[128][64];
    __shared__ float al[128];
    const int t = threadIdx.x;
    const int tx = t & 63, ty = t >> 6;
    const int c0 = blockIdx.x * 64;
    const int r0 = blockIdx.y * 64;
    const int s_base = (r0 - c0 - 63 + 4096) & 4095;

    #pragma unroll
    for (int i = 0; i < 32; ++i) {
        int sr = i * 4 + ty;
        int gs = (s_base + sr) & 4095;
        Vl[sr][tx] = V[(long)gs * IN_F + c0 + tx];
    }
    if (t < 128) al[t] = atopk[(s_base + t) & 4095];
    __syncthreads();

    #pragma unroll
    for (int it = 0; it < 16; ++it) {
        int ry = it * 4 + ty;
        int si = ry - tx + 63;                 // 0..126
        float v = Vl[si][tx] * al[si];
        W[(long)(r0 + ry) * IN_F + c0 + tx] = f2bf(v);
    }
}

// ---------------- x fp32 -> bf16 ------------------------------------------
__global__ __launch_bounds__(256) void cvt_x_kernel(const float* __restrict__ x,
                                                    unsigned short* __restrict__ xb) {
    long i = ((long)blockIdx.x * 256 + threadIdx.x) * 8;
    const float* p = x + i;
    ushort8 o;
    #pragma unroll
    for (int j = 0; j < 8; ++j) o[j] = f2bf(p[j]);
    *(ushort8*)(xb + i) = o;
}

// ---------------- GEMM: C[M][N] = A[M][K] * Bt[N][K]^T  (bf16 -> f32) -----
// 256x256 tile, BK=64, 8 waves (2Mx4N), double-buffered LDS (128 KiB),
// XOR-swizzled LDS (pre-swizzled global source, rule 21), counted vmcnt(8)
// pipeline (loads never drained to 0 in main loop), setprio around MFMA.
__global__ __launch_bounds__(512, 2) void gemm_kernel(const unsigned short* __restrict__ A,
                                                      const unsigned short* __restrict__ Bt,
                                                      float* __restrict__ C) {
    __shared__ unsigned short As[2][256][64];
    __shared__ unsigned short Bs[2][256][64];

    const int tid = threadIdx.x;
    const int l  = tid & 63;
    const int w  = tid >> 6;       // wave 0..7
    const int wr = w >> 2;         // 0..1  (M half)
    const int wc = w & 3;          // 0..3  (N quarter)
    const int lr = l & 15;
    const int kq = l >> 4;         // 0..3
    const int swz = (lr & 7) << 3; // short-index XOR (= byte ^ (row&7)<<4)

    const int bn = blockIdx.x, bm = blockIdx.y;

    const unsigned short* Ab = A  + (long)bm * 256 * IN_F;
    const unsigned short* Bb = Bt + (long)bn * 256 * IN_F;

    // staging geometry: thread t covers LDS shorts [j*4096 + t*8, +8), j=0..3
    // per operand; row = j*64 + (t>>3), chunk = t&7 -> source chunk is
    // pre-swizzled so swizzled ds_reads see logical data.
    const int srow = tid >> 3;                    // 0..63
    const int schunk = (tid & 7) ^ (srow & 7);    // inverse-swizzled source
    const int sdst = tid * 8;                     // shorts

    f32x4 acc[8][4] = {};

#define STAGE(kt, b) do {                                                          \
    const unsigned short* ga_ = Ab + (long)(kt) * 64;                              \
    const unsigned short* gb_ = Bb + (long)(kt) * 64;                              \
    _Pragma("unroll")                                                              \
    for (int j = 0; j < 4; ++j) {                                                  \
        long r_ = (long)(j * 64 + srow);                                           \
        __builtin_amdgcn_global_load_lds((gvoid*)(ga_ + r_ * IN_F + schunk * 8),   \
            (lvoid*)(&As[b][0][0] + j * 4096 + sdst), 16, 0, 0);                   \
    }                                                                              \
    _Pragma("unroll")                                                              \
    for (int j = 0; j < 4; ++j) {                                                  \
        long r_ = (long)(j * 64 + srow);                                           \
        __builtin_amdgcn_global_load_lds((gvoid*)(gb_ + r_ * IN_F + schunk * 8),   \
            (lvoid*)(&Bs[b][0][0] + j * 4096 + sdst), 16, 0, 0);                   \
    }                                                                              \
} while (0)

#define COMPUTE_TILE(b) do {                                                       \
    const unsigned short (*Asb)[64] = As[b];                                       \
    const unsigned short (*Bsb)[64] = Bs[b];                                       \
    bf16x8 aA[4][2], bB[4][2];                                                     \
    _Pragma("unroll")                                                              \
    for (int n = 0; n < 4; ++n)                                                    \
      _Pragma("unroll")                                                            \
      for (int kk = 0; kk < 2; ++kk)                                               \
        bB[n][kk] = *(const bf16x8*)&Bsb[wc * 64 + n * 16 + lr]                    \
                                       [(kk * 32 + kq * 8) ^ swz];                 \
    _Pragma("unroll")                                                              \
    for (int m = 0; m < 4; ++m)                                                    \
      _Pragma("unroll")                                                            \
      for (int kk = 0; kk < 2; ++kk)                                               \
        aA[m][kk] = *(const bf16x8*)&Asb[wr * 128 + m * 16 + lr]                   \
                                        [(kk * 32 + kq * 8) ^ swz];                \
    __builtin_amdgcn_s_setprio(1);                                                 \
    _Pragma("unroll")                                                              \
    for (int m = 0; m < 4; ++m)                                                    \
      _Pragma("unroll")                                                            \
      for (int n = 0; n < 4; ++n)                                                  \
        _Pragma("unroll")                                                          \
        for (int kk = 0; kk < 2; ++kk)                                             \
          acc[m][n] = __builtin_amdgcn_mfma_f32_16x16x32_bf16(aA[m][kk], bB[n][kk],\
                                                              acc[m][n], 0, 0, 0); \
    __builtin_amdgcn_s_setprio(0);                                                 \
    _Pragma("unroll")                                                              \
    for (int m = 0; m < 4; ++m)                                                    \
      _Pragma("unroll")                                                            \
      for (int kk = 0; kk < 2; ++kk)                                               \
        aA[m][kk] = *(const bf16x8*)&Asb[wr * 128 + (m + 4) * 16 + lr]             \
                                        [(kk * 32 + kq * 8) ^ swz];                \
    __builtin_amdgcn_s_setprio(1);                                                 \
    _Pragma("unroll")                                                              \
    for (int m = 0; m < 4; ++m)                                                    \
      _Pragma("unroll")                                                            \
      for (int n = 0; n < 4; ++n)                                                  \
        _Pragma("unroll")                                                          \
        for (int kk = 0; kk < 2; ++kk)                                             \
          acc[m + 4][n] = __builtin_amdgcn_mfma_f32_16x16x32_bf16(aA[m][kk],       \
                                          bB[n][kk], acc[m + 4][n], 0, 0, 0);      \
    __builtin_amdgcn_s_setprio(0);                                                 \
} while (0)

    // prologue: tiles 0 and 1 in flight; wait only for tile 0 (vmcnt 8)
    STAGE(0, 0);
    STAGE(1, 1);
    asm volatile("s_waitcnt vmcnt(8)" ::: "memory");
    __builtin_amdgcn_s_barrier();

    // main loop: compute tile t (buf b) | tile t+1 landing (buf b^1) |
    // after barrier, stage tile t+2 into buf b; vmcnt(8) completes t+1.
    for (int t = 0; t < NT - 2; ++t) {
        const int b = t & 1;
        COMPUTE_TILE(b);
        asm volatile("s_waitcnt lgkmcnt(0)" ::: "memory");
        __builtin_amdgcn_s_barrier();
        STAGE(t + 2, b);
        asm volatile("s_waitcnt vmcnt(8)" ::: "memory");
        __builtin_amdgcn_s_barrier();
    }
    // tail: tiles NT-2 (buf 0) and NT-1 (buf 1)
    COMPUTE_TILE(0);
    asm volatile("s_waitcnt lgkmcnt(0)" ::: "memory");
    __builtin_amdgcn_s_barrier();
    asm volatile("s_waitcnt vmcnt(0)" ::: "memory");
    __builtin_amdgcn_s_barrier();
    COMPUTE_TILE(1);

    // epilogue: C/D layout: col = lane&15, row = (lane>>4)*4 + reg
    const long r0 = (long)bm * 256 + wr * 128;
    const int  c0 = bn * 256 + wc * 64;
    const int  rq = kq * 4;
    #pragma unroll
    for (int m = 0; m < 8; ++m)
        #pragma unroll
        for (int n = 0; n < 4; ++n)
            #pragma unroll
            for (int v = 0; v < 4; ++v)
                C[(r0 + m * 16 + rq + v) * OUT_F + (c0 + n * 16 + lr)] = acc[m][n][v];
#undef STAGE
#undef COMPUTE_TILE
}

extern "C" void kernel_launch(void* const* d_in, const int* in_sizes, int n_in,
                              void* d_out, int out_size, void* d_ws, size_t ws_size,
                              hipStream_t stream) {
    const float* x     = (const float*)d_in[0];
    const float* V     = (const float*)d_in[1];
    const float* alpha = (const float*)d_in[2];
    float* out = (float*)d_out;

    char* ws = (char*)d_ws;
    float* atopk      = (float*)ws;                                        // 16 KB
    unsigned short* W  = (unsigned short*)(ws + 16384);                    // 32 MB
    unsigned short* Xb = (unsigned short*)(ws + 16384 + (size_t)OUT_F * IN_F * 2); // 64 MB

    atopk_kernel<<<1, 256, 0, stream>>>(alpha, atopk);
    build_w_kernel<<<dim3(IN_F / 64, OUT_F / 64), 256, 0, stream>>>(V, atopk, W);
    cvt_x_kernel<<<(BATCH * IN_F / 8) / 256, 256, 0, stream>>>(x, Xb);
    gemm_kernel<<<dim3(OUT_F / 256, BATCH / 256), 512, 0, stream>>>(Xb, W, out);
}